// Round 1
// baseline (632.037 us; speedup 1.0000x reference)
//
#include <hip/hip_runtime.h>
#include <hip/hip_bf16.h>

typedef unsigned short u16;
typedef __attribute__((ext_vector_type(4))) float floatx4;
typedef __attribute__((ext_vector_type(8))) __bf16 bf16x8;

// ---------- helpers ----------
__device__ __forceinline__ u16 f2bf(float f) {
  unsigned int x = __builtin_bit_cast(unsigned int, f);
  unsigned int r = (x + 0x7fffu + ((x >> 16) & 1u)) >> 16;
  return (u16)r;
}
__device__ __forceinline__ float bf2f(u16 u) {
  unsigned int x = ((unsigned int)u) << 16;
  return __builtin_bit_cast(float, x);
}
__device__ __forceinline__ floatx4 mfma16(bf16x8 a, bf16x8 b, floatx4 c) {
  return __builtin_amdgcn_mfma_f32_16x16x32_bf16(a, b, c, 0, 0, 0);
}

// ---------- sizes ----------
#define BB 2
#define SS 2048
#define DM 2048
#define HH 16
#define PCOLS 6144   // qsem 1024 | ksem 1024 | qgeo 1024 | kgeo 1024 | v 2048

// ---------- prep kernels ----------
__global__ void convert_bf16_k(const float* __restrict__ src, u16* __restrict__ dst, size_t n) {
  size_t i = ((size_t)blockIdx.x * blockDim.x + threadIdx.x) * 4;
  if (i + 3 >= n) { for (size_t j = i; j < n; ++j) dst[j] = f2bf(src[j]); return; }
  float4 v = *(const float4*)&src[i];
  u16 o0 = f2bf(v.x), o1 = f2bf(v.y), o2 = f2bf(v.z), o3 = f2bf(v.w);
  ushort4 o; o.x = o0; o.y = o1; o.z = o2; o.w = o3;
  *(ushort4*)&dst[i] = o;
}

// dst[c][r] = bf16(src[r][c]); dst row stride = rows (=K)
__global__ void transpose_w_k(const float* __restrict__ src, u16* __restrict__ dst,
                              int rows, int cols) {
  __shared__ float tile[32][33];
  int c0 = blockIdx.x * 32, r0 = blockIdx.y * 32;
  int tx = threadIdx.x, ty = threadIdx.y;
#pragma unroll
  for (int i = 0; i < 4; ++i)
    tile[ty + i * 8][tx] = src[(size_t)(r0 + ty + i * 8) * cols + c0 + tx];
  __syncthreads();
#pragma unroll
  for (int i = 0; i < 4; ++i)
    dst[(size_t)(c0 + ty + i * 8) * rows + r0 + tx] = f2bf(tile[tx][ty + i * 8]);
}

__global__ void rope_table_k(float* __restrict__ cosT, float* __restrict__ sinT) {
  int idx = blockIdx.x * 256 + threadIdx.x;       // 2048*32
  int s = idx >> 5, d = idx & 31;
  double inv = pow(10000.0, -(double)d / 32.0);
  double ang = (double)s * inv;
  cosT[idx] = (float)cos(ang);
  sinT[idx] = (float)sin(ang);
}

// in-place RoPE on P's qgeo (cols 2048..3071) and kgeo (cols 3072..4095)
__global__ void rope_apply_k(u16* __restrict__ P, const float* __restrict__ cosT,
                             const float* __restrict__ sinT) {
  int idx = blockIdx.x * 256 + threadIdx.x;       // rows(4096)*2*16*32
  int d = idx & 31, h = (idx >> 5) & 15, reg = (idx >> 9) & 1, row = idx >> 10;
  int s = row & (SS - 1);
  size_t base = (size_t)row * PCOLS + (reg ? 3072 : 2048) + h * 64 + d;
  float x1 = bf2f(P[base]), x2 = bf2f(P[base + 32]);
  float c = cosT[s * 32 + d], sn = sinT[s * 32 + d];
  P[base] = f2bf(x1 * c - x2 * sn);
  P[base + 32] = f2bf(x1 * sn + x2 * c);
}

// ---------- GEMM: C(MxN) = A(MxK,bf16) * Bt(NxK,bf16)^T ----------
template <bool OUTF32>
__global__ __launch_bounds__(256, 2)
void gemm_bt_k(const u16* __restrict__ A, const u16* __restrict__ Bt,
               void* __restrict__ Cout, int M, int N, int K) {
  __shared__ alignas(16) u16 As[128][40];
  __shared__ alignas(16) u16 Bs[128][40];
  const int tid = threadIdx.x;
  const int wid = tid >> 6, lane = tid & 63;
  const int lr = lane & 15, lg = lane >> 4;
  const int wr = wid >> 1, wc = wid & 1;
  const int m0 = blockIdx.y * 128, n0 = blockIdx.x * 128;

  floatx4 acc[4][4];
#pragma unroll
  for (int m = 0; m < 4; ++m)
#pragma unroll
    for (int n = 0; n < 4; ++n) acc[m][n] = (floatx4){0.f, 0.f, 0.f, 0.f};

  const int srow = tid >> 2;
  const int scol = (tid & 3) << 3;
  const u16* Abase = A + (size_t)(m0 + srow) * K + scol;
  const u16* Bbase = Bt + (size_t)(n0 + srow) * K + scol;

  for (int k0 = 0; k0 < K; k0 += 32) {
    __syncthreads();
    uint4 av0 = *(const uint4*)(Abase + k0);
    uint4 av1 = *(const uint4*)(Abase + (size_t)64 * K + k0);
    uint4 bv0 = *(const uint4*)(Bbase + k0);
    uint4 bv1 = *(const uint4*)(Bbase + (size_t)64 * K + k0);
    *(uint4*)&As[srow][scol] = av0;
    *(uint4*)&As[srow + 64][scol] = av1;
    *(uint4*)&Bs[srow][scol] = bv0;
    *(uint4*)&Bs[srow + 64][scol] = bv1;
    __syncthreads();

    bf16x8 af[4], bfv[4];
#pragma unroll
    for (int m = 0; m < 4; ++m)
      af[m] = *(const bf16x8*)&As[wr * 64 + m * 16 + lr][lg * 8];
#pragma unroll
    for (int n = 0; n < 4; ++n)
      bfv[n] = *(const bf16x8*)&Bs[wc * 64 + n * 16 + lr][lg * 8];
#pragma unroll
    for (int m = 0; m < 4; ++m)
#pragma unroll
      for (int n = 0; n < 4; ++n)
        acc[m][n] = mfma16(af[m], bfv[n], acc[m][n]);
  }

#pragma unroll
  for (int m = 0; m < 4; ++m) {
    int row0 = m0 + wr * 64 + m * 16 + lg * 4;
#pragma unroll
    for (int n = 0; n < 4; ++n) {
      int col = n0 + wc * 64 + n * 16 + lr;
#pragma unroll
      for (int r = 0; r < 4; ++r) {
        size_t off = (size_t)(row0 + r) * N + col;
        if (OUTF32) ((float*)Cout)[off] = acc[m][n][r];
        else        ((u16*)Cout)[off] = f2bf(acc[m][n][r]);
      }
    }
  }
}

// ---------- flash attention with gated dual scores ----------
__device__ __forceinline__ bf16x8 load_scaled(const u16* p, float s) {
  uint4 raw = *(const uint4*)p;
  const u16* ru = (const u16*)&raw;
  bf16x8 out;
#pragma unroll
  for (int j = 0; j < 8; ++j) out[j] = (__bf16)(bf2f(ru[j]) * s);
  return out;
}

__global__ __launch_bounds__(256, 2)
void attn_k(const u16* __restrict__ P, const float* __restrict__ gate,
            u16* __restrict__ AttO) {
  // grid: x = S/64, y = H, z = B
  const int q0 = blockIdx.x * 64;
  const int h = blockIdx.y, b = blockIdx.z;
  const int tid = threadIdx.x, wid = tid >> 6, lane = tid & 63;
  const int lr = lane & 15, lg = lane >> 4;
  const size_t rowb = (size_t)b * SS;

  const float g = 1.f / (1.f + __expf(-gate[h]));
  const float ssc = g * 0.125f;          // g / sqrt(DS)
  const float gsc = (1.f - g) * 0.125f;  // (1-g) / sqrt(DG)

  __shared__ alignas(16) u16 Ks[32][72];
  __shared__ alignas(16) u16 Kg[32][72];
  __shared__ alignas(16) u16 Vt[128][40];
  __shared__ alignas(16) u16 Pw[4][16][40];

  // Q fragments (rows q0+wid*16+lr), scales folded in
  const int qrow = q0 + wid * 16 + lr;
  const u16* qbase = P + (rowb + qrow) * PCOLS + h * 64;
  bf16x8 qs[2], qg[2];
#pragma unroll
  for (int kk = 0; kk < 2; ++kk) {
    qs[kk] = load_scaled(qbase + kk * 32 + lg * 8, ssc);
    qg[kk] = load_scaled(qbase + 2048 + kk * 32 + lg * 8, gsc);
  }

  float m_r[4] = {-1e30f, -1e30f, -1e30f, -1e30f};
  float l_r[4] = {0.f, 0.f, 0.f, 0.f};
  floatx4 o[8];
#pragma unroll
  for (int n = 0; n < 8; ++n) o[n] = (floatx4){0.f, 0.f, 0.f, 0.f};

  const int nkv = q0 + 64;
  for (int kv0 = 0; kv0 < nkv; kv0 += 32) {
    __syncthreads();
    {
      int r = tid >> 3, cg = (tid & 7) << 3;
      const u16* src = P + (rowb + kv0 + r) * PCOLS;
      *(uint4*)&Ks[r][cg] = *(const uint4*)(src + 1024 + h * 64 + cg);
      *(uint4*)&Kg[r][cg] = *(const uint4*)(src + 3072 + h * 64 + cg);
    }
#pragma unroll
    for (int p = 0; p < 2; ++p) {
      int kv = (tid >> 4) + p * 16, dg = (tid & 15) << 3;
      uint4 v = *(const uint4*)(P + (rowb + kv0 + kv) * PCOLS + 4096 + h * 128 + dg);
      const u16* pv = (const u16*)&v;
#pragma unroll
      for (int j = 0; j < 8; ++j) Vt[dg + j][kv] = pv[j];
    }
    __syncthreads();

    floatx4 sc0 = (floatx4){0.f, 0.f, 0.f, 0.f};
    floatx4 sc1 = (floatx4){0.f, 0.f, 0.f, 0.f};
#pragma unroll
    for (int kk = 0; kk < 2; ++kk) {
      bf16x8 k0f = *(const bf16x8*)&Ks[lr][kk * 32 + lg * 8];
      bf16x8 k1f = *(const bf16x8*)&Ks[16 + lr][kk * 32 + lg * 8];
      bf16x8 g0f = *(const bf16x8*)&Kg[lr][kk * 32 + lg * 8];
      bf16x8 g1f = *(const bf16x8*)&Kg[16 + lr][kk * 32 + lg * 8];
      sc0 = mfma16(qs[kk], k0f, sc0);
      sc0 = mfma16(qg[kk], g0f, sc0);
      sc1 = mfma16(qs[kk], k1f, sc1);
      sc1 = mfma16(qg[kk], g1f, sc1);
    }

    float corr[4];
#pragma unroll
    for (int r = 0; r < 4; ++r) {
      int qr = q0 + wid * 16 + lg * 4 + r;
      float v0 = (kv0 + lr <= qr) ? sc0[r] : -1e30f;
      float v1 = (kv0 + 16 + lr <= qr) ? sc1[r] : -1e30f;
      float mx = fmaxf(v0, v1);
#pragma unroll
      for (int off = 8; off; off >>= 1) mx = fmaxf(mx, __shfl_xor(mx, off));
      float mnew = fmaxf(m_r[r], mx);
      corr[r] = __expf(m_r[r] - mnew);
      float p0 = __expf(v0 - mnew);
      float p1 = __expf(v1 - mnew);
      float ps = p0 + p1;
#pragma unroll
      for (int off = 8; off; off >>= 1) ps += __shfl_xor(ps, off);
      l_r[r] = l_r[r] * corr[r] + ps;
      m_r[r] = mnew;
      Pw[wid][lg * 4 + r][lr] = f2bf(p0);
      Pw[wid][lg * 4 + r][16 + lr] = f2bf(p1);
    }
#pragma unroll
    for (int n = 0; n < 8; ++n)
#pragma unroll
      for (int r = 0; r < 4; ++r) o[n][r] *= corr[r];

    __asm__ volatile("s_waitcnt lgkmcnt(0)" ::: "memory");
    bf16x8 pa = *(const bf16x8*)&Pw[wid][lr][lg * 8];
#pragma unroll
    for (int n = 0; n < 8; ++n) {
      bf16x8 vb = *(const bf16x8*)&Vt[n * 16 + lr][lg * 8];
      o[n] = mfma16(pa, vb, o[n]);
    }
  }

#pragma unroll
  for (int n = 0; n < 8; ++n)
#pragma unroll
    for (int r = 0; r < 4; ++r) {
      float val = o[n][r] / l_r[r];
      AttO[(rowb + q0 + wid * 16 + lg * 4 + r) * (size_t)(HH * 128) + h * 128 + n * 16 + lr] =
          f2bf(val);
    }
}

// ---------- launch ----------
extern "C" void kernel_launch(void* const* d_in, const int* in_sizes, int n_in,
                              void* d_out, int out_size, void* d_ws, size_t ws_size,
                              hipStream_t stream) {
  const float* x       = (const float*)d_in[0];
  const float* wq_sem  = (const float*)d_in[1];
  const float* wk_sem  = (const float*)d_in[2];
  const float* wq_geo  = (const float*)d_in[3];
  const float* wk_geo  = (const float*)d_in[4];
  const float* wv      = (const float*)d_in[5];
  const float* wo      = (const float*)d_in[6];
  const float* gate    = (const float*)d_in[7];

  char* ws = (char*)d_ws;
  // layout (bytes):
  //  Xbf   : 4096*2048*2  = 16,777,216   (reused later as AttO)
  //  WcatT : 6144*2048*2  = 25,165,824
  //  WoT   : 2048*2048*2  =  8,388,608
  //  P     : 4096*6144*2  = 50,331,648
  //  cosT  : 2048*32*4    =     262,144
  //  sinT  : 2048*32*4    =     262,144
  u16* Xbf   = (u16*)(ws);
  u16* WcatT = (u16*)(ws + 16777216);
  u16* WoT   = (u16*)(ws + 16777216 + 25165824);
  u16* P     = (u16*)(ws + 16777216 + 25165824 + 8388608);
  float* cosT = (float*)(ws + 16777216 + 25165824 + 8388608 + 50331648);
  float* sinT = cosT + 2048 * 32;
  u16* AttO = Xbf;  // Xbf dead after projection GEMM

  dim3 tb(32, 8);
  convert_bf16_k<<<8192, 256, 0, stream>>>(x, Xbf, (size_t)4096 * 2048);
  transpose_w_k<<<dim3(32, 64), tb, 0, stream>>>(wq_sem, WcatT + (size_t)0    * 2048, 2048, 1024);
  transpose_w_k<<<dim3(32, 64), tb, 0, stream>>>(wk_sem, WcatT + (size_t)1024 * 2048, 2048, 1024);
  transpose_w_k<<<dim3(32, 64), tb, 0, stream>>>(wq_geo, WcatT + (size_t)2048 * 2048, 2048, 1024);
  transpose_w_k<<<dim3(32, 64), tb, 0, stream>>>(wk_geo, WcatT + (size_t)3072 * 2048, 2048, 1024);
  transpose_w_k<<<dim3(64, 64), tb, 0, stream>>>(wv,     WcatT + (size_t)4096 * 2048, 2048, 2048);
  transpose_w_k<<<dim3(64, 64), tb, 0, stream>>>(wo,     WoT, 2048, 2048);
  rope_table_k<<<256, 256, 0, stream>>>(cosT, sinT);

  gemm_bt_k<false><<<dim3(48, 32), 256, 0, stream>>>(Xbf, WcatT, P, 4096, 6144, 2048);
  rope_apply_k<<<16384, 256, 0, stream>>>(P, cosT, sinT);
  attn_k<<<dim3(32, 16, 2), 256, 0, stream>>>(P, gate, AttO);
  gemm_bt_k<true><<<dim3(16, 32), 256, 0, stream>>>(AttO, WoT, d_out, 4096, 2048, 2048);
}

// Round 2
// 332.909 us; speedup vs baseline: 1.8985x; 1.8985x over previous
//
#include <hip/hip_runtime.h>
#include <hip/hip_bf16.h>

typedef unsigned short u16;
typedef __attribute__((ext_vector_type(4))) float floatx4;
typedef __attribute__((ext_vector_type(8))) __bf16 bf16x8;

// ---------- helpers ----------
__device__ __forceinline__ u16 f2bf(float f) {
  unsigned int x = __builtin_bit_cast(unsigned int, f);
  unsigned int r = (x + 0x7fffu + ((x >> 16) & 1u)) >> 16;
  return (u16)r;
}
__device__ __forceinline__ float bf2f(u16 u) {
  unsigned int x = ((unsigned int)u) << 16;
  return __builtin_bit_cast(float, x);
}
__device__ __forceinline__ floatx4 mfma16(bf16x8 a, bf16x8 b, floatx4 c) {
  return __builtin_amdgcn_mfma_f32_16x16x32_bf16(a, b, c, 0, 0, 0);
}
__device__ __forceinline__ void gload16(const u16* g, u16* l) {
  __builtin_amdgcn_global_load_lds(
      (const __attribute__((address_space(1))) unsigned int*)g,
      (__attribute__((address_space(3))) unsigned int*)l, 16, 0, 0);
}

// ---------- sizes ----------
#define BB 2
#define SS 2048
#define DM 2048
#define HH 16
#define PCOLS 6144   // qsem 1024 | ksem 1024 | qgeo 1024 | kgeo 1024 | v 2048

// ---------- prep kernels ----------
__global__ void convert_bf16_k(const float* __restrict__ src, u16* __restrict__ dst, size_t n) {
  size_t i = ((size_t)blockIdx.x * blockDim.x + threadIdx.x) * 4;
  if (i + 3 >= n) { for (size_t j = i; j < n; ++j) dst[j] = f2bf(src[j]); return; }
  float4 v = *(const float4*)&src[i];
  ushort4 o; o.x = f2bf(v.x); o.y = f2bf(v.y); o.z = f2bf(v.z); o.w = f2bf(v.w);
  *(ushort4*)&dst[i] = o;
}

// dst[c][r] = bf16(src[r][c]); dst row stride = rows (=K)
__global__ void transpose_w_k(const float* __restrict__ src, u16* __restrict__ dst,
                              int rows, int cols) {
  __shared__ float tile[32][33];
  int c0 = blockIdx.x * 32, r0 = blockIdx.y * 32;
  int tx = threadIdx.x, ty = threadIdx.y;
#pragma unroll
  for (int i = 0; i < 4; ++i)
    tile[ty + i * 8][tx] = src[(size_t)(r0 + ty + i * 8) * cols + c0 + tx];
  __syncthreads();
#pragma unroll
  for (int i = 0; i < 4; ++i)
    dst[(size_t)(c0 + ty + i * 8) * rows + r0 + tx] = f2bf(tile[tx][ty + i * 8]);
}

// V transpose: P cols [4096..6144) (bf16) -> VtG[(b*2048 + h*128+dv)][s]
__global__ void vtrans_k(const u16* __restrict__ P, u16* __restrict__ VtG) {
  __shared__ u16 t[32][33];
  int b = blockIdx.z;
  int c0 = blockIdx.x * 32;   // combined (h,dv) index
  int s0 = blockIdx.y * 32;
  int tx = threadIdx.x, ty = threadIdx.y;
#pragma unroll
  for (int i = 0; i < 4; ++i)
    t[ty + i * 8][tx] = P[((size_t)b * SS + s0 + ty + i * 8) * PCOLS + 4096 + c0 + tx];
  __syncthreads();
#pragma unroll
  for (int i = 0; i < 4; ++i)
    VtG[((size_t)b * 2048 + c0 + ty + i * 8) * SS + s0 + tx] = t[tx][ty + i * 8];
}

__global__ void rope_table_k(float* __restrict__ cosT, float* __restrict__ sinT) {
  int idx = blockIdx.x * 256 + threadIdx.x;       // 2048*32
  int s = idx >> 5, d = idx & 31;
  double inv = pow(10000.0, -(double)d / 32.0);
  double ang = (double)s * inv;
  cosT[idx] = (float)cos(ang);
  sinT[idx] = (float)sin(ang);
}

// in-place RoPE on P's qgeo (cols 2048..3071) and kgeo (cols 3072..4095)
__global__ void rope_apply_k(u16* __restrict__ P, const float* __restrict__ cosT,
                             const float* __restrict__ sinT) {
  int idx = blockIdx.x * 256 + threadIdx.x;       // rows(4096)*2*16*32
  int d = idx & 31, h = (idx >> 5) & 15, reg = (idx >> 9) & 1, row = idx >> 10;
  int s = row & (SS - 1);
  size_t base = (size_t)row * PCOLS + (reg ? 3072 : 2048) + h * 64 + d;
  float x1 = bf2f(P[base]), x2 = bf2f(P[base + 32]);
  float c = cosT[s * 32 + d], sn = sinT[s * 32 + d];
  P[base] = f2bf(x1 * c - x2 * sn);
  P[base + 32] = f2bf(x1 * sn + x2 * c);
}

// ---------- GEMM (m97 structure): C(MxN) = A(MxK,bf16) * Bt(NxK,bf16)^T ----------
// 128x128 tile, BK=32, unpadded LDS, global_load_lds width 16.
template <bool OUTF32>
__global__ __launch_bounds__(256, 2)
void gemm_bt_k(const u16* __restrict__ A, const u16* __restrict__ Bt,
               void* __restrict__ Cout, int M, int N, int K) {
  __shared__ alignas(16) u16 As[128 * 32];
  __shared__ alignas(16) u16 Bs[128 * 32];
  const int tid = threadIdx.x;
  const int wid = tid >> 6, lane = tid & 63;
  const int lr = lane & 15, lg = lane >> 4;
  const int wr = wid >> 1, wc = wid & 1;
  const int m0 = blockIdx.y * 128, n0 = blockIdx.x * 128;

  floatx4 acc[4][4];
#pragma unroll
  for (int m = 0; m < 4; ++m)
#pragma unroll
    for (int n = 0; n < 4; ++n) acc[m][n] = (floatx4){0.f, 0.f, 0.f, 0.f};

  // staging: wave w covers rows [w*32, w*32+32); lane l -> row w*32 + (l>>2) (+16), col (l&3)*8
  const int srow = wid * 32 + (lane >> 2);
  const int scol = (lane & 3) * 8;
  const u16* Ag0 = A + (size_t)(m0 + srow) * K + scol;
  const u16* Ag1 = Ag0 + (size_t)16 * K;
  const u16* Bg0 = Bt + (size_t)(n0 + srow) * K + scol;
  const u16* Bg1 = Bg0 + (size_t)16 * K;
  u16* Al0 = As + wid * 32 * 32;   // wave-uniform LDS base (linear: base + lane*16B)
  u16* Al1 = Al0 + 16 * 32;
  u16* Bl0 = Bs + wid * 32 * 32;
  u16* Bl1 = Bl0 + 16 * 32;

  for (int k0 = 0; k0 < K; k0 += 32) {
    __syncthreads();
    gload16(Ag0 + k0, Al0);
    gload16(Ag1 + k0, Al1);
    gload16(Bg0 + k0, Bl0);
    gload16(Bg1 + k0, Bl1);
    __syncthreads();   // compiler emits vmcnt(0) drain before barrier

    bf16x8 af[4], bfv[4];
#pragma unroll
    for (int m = 0; m < 4; ++m)
      af[m] = *(const bf16x8*)&As[(wr * 64 + m * 16 + lr) * 32 + lg * 8];
#pragma unroll
    for (int n = 0; n < 4; ++n)
      bfv[n] = *(const bf16x8*)&Bs[(wc * 64 + n * 16 + lr) * 32 + lg * 8];
#pragma unroll
    for (int m = 0; m < 4; ++m)
#pragma unroll
      for (int n = 0; n < 4; ++n)
        acc[m][n] = mfma16(af[m], bfv[n], acc[m][n]);
  }

#pragma unroll
  for (int m = 0; m < 4; ++m) {
    int row0 = m0 + wr * 64 + m * 16 + lg * 4;
#pragma unroll
    for (int n = 0; n < 4; ++n) {
      int col = n0 + wc * 64 + n * 16 + lr;
#pragma unroll
      for (int r = 0; r < 4; ++r) {
        size_t off = (size_t)(row0 + r) * N + col;
        if (OUTF32) ((float*)Cout)[off] = acc[m][n][r];
        else        ((u16*)Cout)[off] = f2bf(acc[m][n][r]);
      }
    }
  }
}

// ---------- flash attention with gated dual scores (KVB=64) ----------
__device__ __forceinline__ bf16x8 load_scaled(const u16* p, float s) {
  uint4 raw = *(const uint4*)p;
  const u16* ru = (const u16*)&raw;
  bf16x8 out;
#pragma unroll
  for (int j = 0; j < 8; ++j) out[j] = (__bf16)(bf2f(ru[j]) * s);
  return out;
}

__global__ __launch_bounds__(256, 2)
void attn_k(const u16* __restrict__ P, const u16* __restrict__ VtG,
            const float* __restrict__ gate, u16* __restrict__ AttO) {
  // grid: x = 512 (combined rev-qblock, head), y = B. Heavy q-blocks dispatch first.
  const int qbrev = blockIdx.x >> 4;
  const int h = blockIdx.x & 15;
  const int q0 = (31 - qbrev) * 64;
  const int b = blockIdx.y;
  const int tid = threadIdx.x, wid = tid >> 6, lane = tid & 63;
  const int lr = lane & 15, lg = lane >> 4;
  const size_t rowb = (size_t)b * SS;

  const float g = 1.f / (1.f + __expf(-gate[h]));
  const float ssc = g * 0.125f;          // g / sqrt(DS)
  const float gsc = (1.f - g) * 0.125f;  // (1-g) / sqrt(DG)

  __shared__ alignas(16) u16 Ks[64][72];
  __shared__ alignas(16) u16 Kg[64][72];
  __shared__ alignas(16) u16 Vt[128][72];
  __shared__ alignas(16) u16 Pw[4][16][72];

  // Q fragments (A-rows = q0 + wid*16 + lr), gate+scale folded in
  const u16* qbase = P + (rowb + q0 + wid * 16 + lr) * PCOLS + h * 64;
  bf16x8 qs[2], qg[2];
#pragma unroll
  for (int kk = 0; kk < 2; ++kk) {
    qs[kk] = load_scaled(qbase + kk * 32 + lg * 8, ssc);
    qg[kk] = load_scaled(qbase + 2048 + kk * 32 + lg * 8, gsc);
  }

  float m_r[4] = {-1e30f, -1e30f, -1e30f, -1e30f};
  float l_r[4] = {0.f, 0.f, 0.f, 0.f};
  floatx4 o[8];
#pragma unroll
  for (int n = 0; n < 8; ++n) o[n] = (floatx4){0.f, 0.f, 0.f, 0.f};

  const int srow = tid >> 3;           // 0..31
  const int sc8 = (tid & 7) * 8;       // 0..56

  const int nkv = q0 + 64;
  for (int kv0 = 0; kv0 < nkv; kv0 += 64) {
    __syncthreads();
    // stage K_sem, K_geo: 64 rows x 64 u16, coalesced uint4
#pragma unroll
    for (int i = 0; i < 2; ++i) {
      int r = i * 32 + srow;
      const u16* src = P + (rowb + kv0 + r) * PCOLS;
      *(uint4*)&Ks[r][sc8] = *(const uint4*)(src + 1024 + h * 64 + sc8);
      *(uint4*)&Kg[r][sc8] = *(const uint4*)(src + 3072 + h * 64 + sc8);
    }
    // stage V^T: 128 rows (dv) x 64 u16 (kv), coalesced uint4
#pragma unroll
    for (int i = 0; i < 4; ++i) {
      int r = i * 32 + srow;
      *(uint4*)&Vt[r][sc8] =
          *(const uint4*)&VtG[((size_t)b * 2048 + h * 128 + r) * SS + kv0 + sc8];
    }
    __syncthreads();

    // QK^T: 4 kv-subtiles of 16
    floatx4 sc[4];
#pragma unroll
    for (int s = 0; s < 4; ++s) sc[s] = (floatx4){0.f, 0.f, 0.f, 0.f};
#pragma unroll
    for (int kk = 0; kk < 2; ++kk) {
#pragma unroll
      for (int s = 0; s < 4; ++s) {
        bf16x8 kf = *(const bf16x8*)&Ks[s * 16 + lr][kk * 32 + lg * 8];
        bf16x8 gf = *(const bf16x8*)&Kg[s * 16 + lr][kk * 32 + lg * 8];
        sc[s] = mfma16(qs[kk], kf, sc[s]);
        sc[s] = mfma16(qg[kk], gf, sc[s]);
      }
    }

    const bool needmask = (kv0 + 63 > q0 + wid * 16);
    float corr[4];
#pragma unroll
    for (int r = 0; r < 4; ++r) {
      int qr = q0 + wid * 16 + lg * 4 + r;
      float v0 = sc[0][r], v1 = sc[1][r], v2 = sc[2][r], v3 = sc[3][r];
      if (needmask) {
        v0 = (kv0 + lr      <= qr) ? v0 : -1e30f;
        v1 = (kv0 + 16 + lr <= qr) ? v1 : -1e30f;
        v2 = (kv0 + 32 + lr <= qr) ? v2 : -1e30f;
        v3 = (kv0 + 48 + lr <= qr) ? v3 : -1e30f;
      }
      float mx = fmaxf(fmaxf(v0, v1), fmaxf(v2, v3));
#pragma unroll
      for (int off = 8; off; off >>= 1) mx = fmaxf(mx, __shfl_xor(mx, off));
      float mnew = fmaxf(m_r[r], mx);
      corr[r] = __expf(m_r[r] - mnew);
      float p0 = __expf(v0 - mnew), p1 = __expf(v1 - mnew);
      float p2 = __expf(v2 - mnew), p3 = __expf(v3 - mnew);
      float ps = p0 + p1 + p2 + p3;
#pragma unroll
      for (int off = 8; off; off >>= 1) ps += __shfl_xor(ps, off);
      l_r[r] = l_r[r] * corr[r] + ps;
      m_r[r] = mnew;
      Pw[wid][lg * 4 + r][lr]      = f2bf(p0);
      Pw[wid][lg * 4 + r][16 + lr] = f2bf(p1);
      Pw[wid][lg * 4 + r][32 + lr] = f2bf(p2);
      Pw[wid][lg * 4 + r][48 + lr] = f2bf(p3);
    }
#pragma unroll
    for (int n = 0; n < 8; ++n)
#pragma unroll
      for (int r = 0; r < 4; ++r) o[n][r] *= corr[r];

    __asm__ volatile("s_waitcnt lgkmcnt(0)" ::: "memory");
    bf16x8 pa0 = *(const bf16x8*)&Pw[wid][lr][lg * 8];
    bf16x8 pa1 = *(const bf16x8*)&Pw[wid][lr][32 + lg * 8];
#pragma unroll
    for (int n = 0; n < 8; ++n) {
      bf16x8 vb0 = *(const bf16x8*)&Vt[n * 16 + lr][lg * 8];
      bf16x8 vb1 = *(const bf16x8*)&Vt[n * 16 + lr][32 + lg * 8];
      o[n] = mfma16(pa0, vb0, o[n]);
      o[n] = mfma16(pa1, vb1, o[n]);
    }
  }

#pragma unroll
  for (int n = 0; n < 8; ++n)
#pragma unroll
    for (int r = 0; r < 4; ++r) {
      float val = o[n][r] / l_r[r];
      AttO[(rowb + q0 + wid * 16 + lg * 4 + r) * (size_t)(HH * 128) + h * 128 + n * 16 + lr] =
          f2bf(val);
    }
}

// ---------- launch ----------
extern "C" void kernel_launch(void* const* d_in, const int* in_sizes, int n_in,
                              void* d_out, int out_size, void* d_ws, size_t ws_size,
                              hipStream_t stream) {
  const float* x       = (const float*)d_in[0];
  const float* wq_sem  = (const float*)d_in[1];
  const float* wk_sem  = (const float*)d_in[2];
  const float* wq_geo  = (const float*)d_in[3];
  const float* wk_geo  = (const float*)d_in[4];
  const float* wv      = (const float*)d_in[5];
  const float* wo      = (const float*)d_in[6];
  const float* gate    = (const float*)d_in[7];

  char* ws = (char*)d_ws;
  // layout (bytes):
  //  Xbf   : 4096*2048*2  = 16,777,216   (reused later as AttO)
  //  WcatT : 6144*2048*2  = 25,165,824   (reused later as VtG, 16MB)
  //  WoT   : 2048*2048*2  =  8,388,608
  //  P     : 4096*6144*2  = 50,331,648
  //  cosT/sinT: 2x 262,144
  u16* Xbf   = (u16*)(ws);
  u16* WcatT = (u16*)(ws + 16777216);
  u16* WoT   = (u16*)(ws + 16777216 + 25165824);
  u16* P     = (u16*)(ws + 16777216 + 25165824 + 8388608);
  float* cosT = (float*)(ws + 16777216 + 25165824 + 8388608 + 50331648);
  float* sinT = cosT + 2048 * 32;
  u16* AttO = Xbf;    // Xbf dead after projection GEMM
  u16* VtG  = WcatT;  // WcatT dead after projection GEMM

  dim3 tb(32, 8);
  convert_bf16_k<<<8192, 256, 0, stream>>>(x, Xbf, (size_t)4096 * 2048);
  transpose_w_k<<<dim3(32, 64), tb, 0, stream>>>(wq_sem, WcatT + (size_t)0    * 2048, 2048, 1024);
  transpose_w_k<<<dim3(32, 64), tb, 0, stream>>>(wk_sem, WcatT + (size_t)1024 * 2048, 2048, 1024);
  transpose_w_k<<<dim3(32, 64), tb, 0, stream>>>(wq_geo, WcatT + (size_t)2048 * 2048, 2048, 1024);
  transpose_w_k<<<dim3(32, 64), tb, 0, stream>>>(wk_geo, WcatT + (size_t)3072 * 2048, 2048, 1024);
  transpose_w_k<<<dim3(64, 64), tb, 0, stream>>>(wv,     WcatT + (size_t)4096 * 2048, 2048, 2048);
  transpose_w_k<<<dim3(64, 64), tb, 0, stream>>>(wo,     WoT, 2048, 2048);
  rope_table_k<<<256, 256, 0, stream>>>(cosT, sinT);

  gemm_bt_k<false><<<dim3(48, 32), 256, 0, stream>>>(Xbf, WcatT, P, 4096, 6144, 2048);
  rope_apply_k<<<16384, 256, 0, stream>>>(P, cosT, sinT);
  vtrans_k<<<dim3(64, 64, 2), tb, 0, stream>>>(P, VtG);
  attn_k<<<dim3(512, 2), 256, 0, stream>>>(P, VtG, gate, AttO);
  gemm_bt_k<true><<<dim3(16, 32), 256, 0, stream>>>(AttO, WoT, d_out, 4096, 2048, 2048);
}